// Round 15
// baseline (169.396 us; speedup 1.0000x reference)
//
#include <hip/hip_runtime.h>

typedef unsigned short u16;
typedef unsigned int u32;
typedef __attribute__((ext_vector_type(8))) short short8;    // 8 bf16
typedef __attribute__((ext_vector_type(16))) float f32x16;

#define BB 8
#define NN 4096
#define NPP 1024
#define NSS 32
#define CFF 64
#define C0 67
#define H0 64
#define H1 128
#define H2 256
#define MTOT (BB*NPP*NSS)   // 262144
#define BN_EPS 1e-5f
#define INV_M (1.0f/262144.0f)

#define MFMA32(a,b,c) __builtin_amdgcn_mfma_f32_32x32x16_bf16(a,b,c,0,0,0)

__device__ __forceinline__ float bf2f(u16 h){ return __uint_as_float(((u32)h)<<16); }
__device__ __forceinline__ u16 f2bf(float f){
  u32 u = __float_as_uint(f);
  u32 r = (u + 0x7fffu + ((u>>16)&1u)) >> 16;
  return (u16)r;
}
__device__ __forceinline__ u32 pack2(float a, float b){
  return (u32)f2bf(a) | ((u32)f2bf(b)<<16);
}

// ---------------------------------------------------------------------------
// R15 = R14 (verified ~167 us structure) + two mathematically-identical cuts:
//   (a) k_l0: K padded to 10 chunks (80) instead of 12 (96) — chunks 10-11
//       were entirely zero. MFMA/wave 12->10, XLc 24->20KB (LDS 36->32KB).
//   (b) k_final: select mxp-vs-mnp POINTER by sign(sc) before the loop —
//       halves its read traffic (was loading both then selecting the value).
// Structural alternatives all tested & closed (see R14 header): software
// barriers 2.7x slower, cooperative launch no-op, persistent loops spill,
// Gram stats null. 5-dispatch pipeline = practical optimum here.
//
// Chunked-K layout: [k/8][row][8 bf16]; MFMA 32x32x16: A[m=lane&31][k=(lane>>5)*8+j]
// (k-perm consistent across A/B => exact), C/D col=lane&31,
// row=(reg&3)+8*(reg>>2)+4*(lane>>5).
//
// ws layout (bytes), total 46,280,704:
//   stats [0,49152) | Wt0c [49152,61440) | Wt1c [61440,77824) | Wt2c [77824,143360)
//   ptsT [143360,4337664) | y0 [4337664,37892096) | mxp [37892096,42086400)
//   mnp [42086400,46280704)
// ---------------------------------------------------------------------------
#define WS_NEED 46280704u

__global__ __launch_bounds__(256) void k_setup(
    const float* __restrict__ xyz, const float* __restrict__ points,
    const int* __restrict__ sidx,
    const float* __restrict__ W0, const float* __restrict__ W1, const float* __restrict__ W2,
    u16* __restrict__ ptsT, u16* __restrict__ Wt0c, u16* __restrict__ Wt1c,
    u16* __restrict__ Wt2c, float* __restrict__ out_newxyz, float* __restrict__ stats)
{
  int blk = blockIdx.x, tid = threadIdx.x;
  if (blk < 512) {
    __shared__ float t[64][68];          // pad 68: 16B-aligned rows, conflict-free
    int b = blk >> 6, n0 = (blk & 63) << 6;
    for (int it = 0; it < 4; ++it) {
      int u = it*256 + tid;              // 1024 units
      int nq = u & 15, c = u >> 4;       // c 0..63
      float4 v = *(const float4*)&points[(size_t)(b*CFF + c)*NN + n0 + nq*4];
      *(float4*)&t[c][nq*4] = v;
    }
    __syncthreads();
    for (int it = 0; it < 2; ++it) {
      int u = it*256 + tid;              // 512 units
      int oct = u & 7, n = u >> 3;       // n 0..63
      u16 pk[8];
#pragma unroll
      for (int j = 0; j < 8; ++j) pk[j] = f2bf(t[oct*8 + j][n]);
      *(uint4*)&ptsT[((size_t)(b*NN + n0 + n))*CFF + oct*8] = *(uint4*)pk;
    }
  } else if (blk < 544) {
    int t0 = (blk - 512)*256 + tid;
    int b = t0 >> 10;
    int s = sidx[t0];
    for (int k = 0; k < 3; ++k)
      out_newxyz[(size_t)t0*3 + k] = xyz[((size_t)(b*NN + s))*3 + k];
  } else if (blk == 544) {
    for (int i = 0; i < 24; ++i) {
      int e = i*256 + tid;                 // [12 kc][64 o][8 j]
      int kc = e >> 9, o = (e >> 3) & 63, j = e & 7, k = kc*8 + j;
      float v = (k < 64) ? W0[o*C0 + 3 + k] : ((k < 67) ? W0[o*C0 + (k - 64)] : 0.f);
      Wt0c[e] = f2bf(v);
    }
  } else if (blk == 545) {
    for (int i = 0; i < 32; ++i) {
      int e = i*256 + tid;                 // [8 kc][128 n][8 j]
      int kc = e >> 10, n = (e >> 3) & 127, j = e & 7;
      Wt1c[e] = f2bf(W1[n*H0 + kc*8 + j]);
    }
  } else if (blk == 554) {
    // zero the 3x4096-float stats region (replaces hipMemsetAsync dispatch)
    float4 z = {0.f, 0.f, 0.f, 0.f};
    float4* p = (float4*)stats;
#pragma unroll
    for (int i = 0; i < 12; ++i) p[i*256 + tid] = z;
  } else {
    int base = (blk - 546) * 4096;
    for (int i = 0; i < 16; ++i) {
      int e = base + i*256 + tid;          // [16 kc][256 n][8 j]
      int kc = e >> 11, n = (e >> 3) & 255, j = e & 7;
      Wt2c[e] = f2bf(W2[n*H1 + kc*8 + j]);
    }
  }
}

__global__ __launch_bounds__(256) void k_xyz_only(
    const float* __restrict__ xyz, const int* __restrict__ sidx, float* __restrict__ out_newxyz)
{
  int t0 = blockIdx.x*256 + threadIdx.x;
  int b = t0 >> 10;
  int s = sidx[t0];
  for (int k = 0; k < 3; ++k)
    out_newxyz[(size_t)t0*3 + k] = xyz[((size_t)(b*NN + s))*3 + k];
}

// ---------------------------------------------------------------------------
// L0: M=128, K=80 (10 chunks; ch 67-79 zero), Cout=64. 10 MFMA/wave.
// Epilogue: LDS transpose -> coalesced dwordx4 y0 stores. LDS 32KB.
// ---------------------------------------------------------------------------
__global__ __launch_bounds__(256) void k_l0(
    const float* __restrict__ xyz, const int* __restrict__ sidx, const int* __restrict__ nidx,
    const u16* __restrict__ ptsT, const u16* __restrict__ Wt0c,
    u16* __restrict__ y0, float* __restrict__ stats)
{
  __shared__ u16 XLc[10*128*8];  // 20 KB (reused as 16 KB C-stage in epilogue)
  __shared__ u16 W0c[12*64*8];   // 12 KB (stage all 12 chunks of Wt0c; use 10)
  int tid = threadIdx.x;
  int m0 = blockIdx.x * 128;
  int b = m0 >> 15;

  for (int i = 0; i < 3; ++i)
    ((uint4*)W0c)[i*256 + tid] = ((const uint4*)Wt0c)[i*256 + tid];

  int pos = tid & 127, half = tid >> 7;
  int m = m0 + pos;
  int nb = nidx[m];
  {
    const uint4* prow = (const uint4*)(ptsT + ((size_t)(b*NN + nb))*CFF + half*32);
    uint4 h0 = prow[0], h1 = prow[1], h2 = prow[2], h3 = prow[3];
    *(uint4*)&XLc[((half*4+0)*128 + pos)*8] = h0;
    *(uint4*)&XLc[((half*4+1)*128 + pos)*8] = h1;
    *(uint4*)&XLc[((half*4+2)*128 + pos)*8] = h2;
    *(uint4*)&XLc[((half*4+3)*128 + pos)*8] = h3;
    if (half == 0) {
      int p = (m & 32767) >> 5;
      int sp = sidx[b*NPP + p];
      float r0 = xyz[((size_t)(b*NN+nb))*3+0] - xyz[((size_t)(b*NN+sp))*3+0];
      float r1 = xyz[((size_t)(b*NN+nb))*3+1] - xyz[((size_t)(b*NN+sp))*3+1];
      float r2 = xyz[((size_t)(b*NN+nb))*3+2] - xyz[((size_t)(b*NN+sp))*3+2];
      uint4 v = { pack2(r0, r1), pack2(r2, 0.f), 0u, 0u };
      *(uint4*)&XLc[(8*128 + pos)*8] = v;       // chunk 8: r0,r1,r2 + zeros
    } else {
      uint4 z = {0u,0u,0u,0u};
      *(uint4*)&XLc[(9*128 + pos)*8] = z;       // chunk 9: zero pad (K 72..79)
    }
  }
  __syncthreads();

  int lane = tid & 63, wv = tid >> 6;
  int l31 = lane & 31, kh = lane >> 5;
  int nt = wv & 1, mtb = (wv >> 1) * 2;
  f32x16 acc[2];
  for (int mi = 0; mi < 2; ++mi) for (int r = 0; r < 16; ++r) acc[mi][r] = 0.f;

  for (int kt = 0; kt < 5; ++kt) {              // 10 chunks (was 12; 10-11 were zero)
    int ck = kt*2 + kh;
    short8 bfrag = *(const short8*)&W0c[(ck*64 + nt*32 + l31)*8];
    for (int mi = 0; mi < 2; ++mi) {
      short8 afrag = *(const short8*)&XLc[(ck*128 + (mtb+mi)*32 + l31)*8];
      acc[mi] = MFMA32(afrag, bfrag, acc[mi]);
    }
  }

  float s = 0.f, q = 0.f;
  for (int mi = 0; mi < 2; ++mi)
    for (int r = 0; r < 16; ++r) { float y = acc[mi][r]; s += y; q += y*y; }
  s += __shfl_xor(s, 32); q += __shfl_xor(q, 32);
  if (lane < 32) {
    int slot = blockIdx.x & 7;
    atomicAdd(&stats[slot*256 + nt*32 + lane], s);
    atomicAdd(&stats[2048 + slot*256 + nt*32 + lane], q);
  }

  // ---- coalesced y0 write: scatter to LDS (reuse XLc), then dwordx4 ----
  __syncthreads();   // all MFMA ds_reads of XLc complete
  {
    int chx = (nt*32 + l31) ^ (kh*32);   // = l31 + 32*(nt^kh)
#pragma unroll
    for (int mi = 0; mi < 2; ++mi)
#pragma unroll
      for (int r = 0; r < 16; ++r) {
        int mm = (mtb+mi)*32 + (r&3) + 8*(r>>2) + 4*kh;   // mm bit2 == kh
        XLc[mm*64 + chx] = f2bf(acc[mi][r]);
      }
  }
  __syncthreads();
  {
    uint4* dst = (uint4*)(y0 + (size_t)m0*H0);
#pragma unroll
    for (int i = 0; i < 4; ++i) {
      int t16 = i*256 + tid;                 // 16B unit
      int mrow = t16 >> 3, ch0 = (t16 & 7)*8;
      int idx = mrow*64 + (ch0 ^ (32*((mrow>>2)&1)));
      dst[t16] = *(const uint4*)&XLc[idx];
    }
  }
}

// ---------------------------------------------------------------------------
// L1 stats v2: M=128, BN0+ReLU staged in 16KB X0c; W1 B-fragments DIRECT from
// global (per-wave coalesced 512B, issued before any barrier). (256,4).
// ---------------------------------------------------------------------------
__global__ __launch_bounds__(256, 4) void k_l1s(
    const u16* __restrict__ y0, const u16* __restrict__ Wt1c,
    const float* __restrict__ g0, const float* __restrict__ e0,
    const float* __restrict__ stIn, float* __restrict__ stOut)
{
  __shared__ u16 X0c[8*128*8];   // 16 KB
  __shared__ float scl0[64], sft0[64];
  int tid = threadIdx.x;
  int m0 = blockIdx.x * 128;
  int lane = tid & 63, wv = tid >> 6;
  int l31 = lane & 31, kh = lane >> 5;

  // early global loads: y0 row + B fragments (no LDS dependency)
  int pos = tid & 127, half = tid >> 7;
  u16 hs[32];
  {
    const u16* row = y0 + (size_t)(m0 + pos)*H0 + half*32;
#pragma unroll
    for (int t = 0; t < 4; ++t) *(uint4*)&hs[t*8] = ((const uint4*)row)[t];
  }
  short8 b1[4];
#pragma unroll
  for (int kt = 0; kt < 4; ++kt)
    b1[kt] = *(const short8*)&Wt1c[((kt*2 + kh)*128 + wv*32 + l31)*8];

  if (tid < 64) {
    float s = 0.f, q = 0.f;
    for (int sl = 0; sl < 8; ++sl) { s += stIn[sl*256 + tid]; q += stIn[2048 + sl*256 + tid]; }
    float mu = s*INV_M, var = q*INV_M - mu*mu;
    float sc = g0[tid] * rsqrtf(var + BN_EPS);
    scl0[tid] = sc; sft0[tid] = e0[tid] - mu*sc;
  }
  __syncthreads();   // scl0 ready

  {
    u16 ob[32];
#pragma unroll
    for (int j = 0; j < 32; ++j) {
      int c = half*32 + j;
      ob[j] = f2bf(fmaxf(fmaf(scl0[c], bf2f(hs[j]), sft0[c]), 0.f));
    }
#pragma unroll
    for (int t = 0; t < 4; ++t)
      *(uint4*)&X0c[((half*4+t)*128 + pos)*8] = *(uint4*)&ob[t*8];
  }
  __syncthreads();

  f32x16 acc[4];
#pragma unroll
  for (int mt = 0; mt < 4; ++mt) for (int r = 0; r < 16; ++r) acc[mt][r] = 0.f;

#pragma unroll
  for (int kt = 0; kt < 4; ++kt) {
    int ck = kt*2 + kh;
#pragma unroll
    for (int mt = 0; mt < 4; ++mt) {
      short8 afrag = *(const short8*)&X0c[(ck*128 + mt*32 + l31)*8];
      acc[mt] = MFMA32(afrag, b1[kt], acc[mt]);
    }
  }

  float s = 0.f, q = 0.f;
#pragma unroll
  for (int mt = 0; mt < 4; ++mt)
#pragma unroll
    for (int r = 0; r < 16; ++r) { float y = acc[mt][r]; s += y; q += y*y; }
  s += __shfl_xor(s, 32); q += __shfl_xor(q, 32);
  if (lane < 32) {
    int slot = blockIdx.x & 7;
    atomicAdd(&stOut[slot*256 + wv*32 + lane], s);
    atomicAdd(&stOut[2048 + slot*256 + wv*32 + lane], q);
  }
}

// ---------------------------------------------------------------------------
// L2 fused v4: M=64, 256 threads, 24KB LDS, no weight staging (W1/W2 direct
// per-wave register fragments from L2-hot Wt1c/Wt2c). (256,4). 3 barriers.
// X1c row-XOR-swizzle by (cb&3) as verified in R2.
// ---------------------------------------------------------------------------
__global__ __launch_bounds__(256, 4) void k_l2f(
    const u16* __restrict__ y0, const u16* __restrict__ Wt1c, const u16* __restrict__ Wt2c,
    const float* __restrict__ g0, const float* __restrict__ e0,
    const float* __restrict__ g1, const float* __restrict__ e1,
    const float* __restrict__ st0, const float* __restrict__ st1, float* __restrict__ stOut,
    u16* __restrict__ mxp, u16* __restrict__ mnp)
{
  __shared__ u16 X0c[8*64*8];     // 8 KB
  __shared__ u16 X1c[16*64*8];    // 16 KB, rows XOR-swizzled by (cb&3)
  __shared__ float scl0[64], sft0[64], scl1[128], sft1[128];
  int tid = threadIdx.x;
  int m0 = blockIdx.x * 64;
  int lane = tid & 63, wv = tid >> 6;
  int l31 = lane & 31, kh = lane >> 5;

  // early global loads: y0 rows + W1 fragments
  int pos = tid & 63, grp = tid >> 6;
  u16 hs[16];
  {
    const u16* row = y0 + (size_t)(m0 + pos)*H0 + grp*16;
    *(uint4*)&hs[0] = ((const uint4*)row)[0];
    *(uint4*)&hs[8] = ((const uint4*)row)[1];
  }
  short8 b1[4];
#pragma unroll
  for (int kt = 0; kt < 4; ++kt)
    b1[kt] = *(const short8*)&Wt1c[((kt*2 + kh)*128 + wv*32 + l31)*8];

  if (tid < 64) {
    float s = 0.f, q = 0.f;
    for (int sl = 0; sl < 8; ++sl) { s += st0[sl*256 + tid]; q += st0[2048 + sl*256 + tid]; }
    float mu = s*INV_M, var = q*INV_M - mu*mu;
    float sc = g0[tid] * rsqrtf(var + BN_EPS);
    scl0[tid] = sc; sft0[tid] = e0[tid] - mu*sc;
  }
  if (tid < 128) {
    float s = 0.f, q = 0.f;
    for (int sl = 0; sl < 8; ++sl) { s += st1[sl*256 + tid]; q += st1[2048 + sl*256 + tid]; }
    float mu = s*INV_M, var = q*INV_M - mu*mu;
    float sc = g1[tid] * rsqrtf(var + BN_EPS);
    scl1[tid] = sc; sft1[tid] = e1[tid] - mu*sc;
  }
  __syncthreads();   // scl0/scl1 ready

  // BN0+ReLU -> X0c
  {
    u16 ob[16];
#pragma unroll
    for (int j = 0; j < 16; ++j) {
      int c = grp*16 + j;
      ob[j] = f2bf(fmaxf(fmaf(scl0[c], bf2f(hs[j]), sft0[c]), 0.f));
    }
    *(uint4*)&X0c[((2*grp)*64 + pos)*8]   = *(uint4*)&ob[0];
    *(uint4*)&X0c[((2*grp+1)*64 + pos)*8] = *(uint4*)&ob[8];
  }
  __syncthreads();

  // ---- GEMM1: wave wv -> out-ch wv*32+l31, rows mt*32 (mt 0..1) ----
  f32x16 acc1[2];
#pragma unroll
  for (int mt = 0; mt < 2; ++mt) for (int r = 0; r < 16; ++r) acc1[mt][r] = 0.f;
#pragma unroll
  for (int kt = 0; kt < 4; ++kt) {
    int ck = kt*2 + kh;
#pragma unroll
    for (int mt = 0; mt < 2; ++mt) {
      short8 afrag = *(const short8*)&X0c[(ck*64 + mt*32 + l31)*8];
      acc1[mt] = MFMA32(afrag, b1[kt], acc1[mt]);
    }
  }

  // ---- BN1+ReLU scatter C->A into X1c (row XOR-swizzled by cb&3) ----
  {
    int ch1 = wv*32 + l31;
    int cb = ch1 >> 3, cr = ch1 & 7, sw = cb & 3;
    float sc1 = scl1[ch1], sf1 = sft1[ch1];
#pragma unroll
    for (int mt = 0; mt < 2; ++mt)
#pragma unroll
      for (int r = 0; r < 16; ++r) {
        int mm = mt*32 + (r&3) + 8*(r>>2) + 4*kh;
        X1c[(cb*64 + (mm ^ sw))*8 + cr] = f2bf(fmaxf(fmaf(sc1, acc1[mt][r], sf1), 0.f));
      }
  }
  __syncthreads();

  // ---- GEMM2: wave wv -> out-ch wv*64 + nt*32 + l31; K=128, k4 0..7 ----
  f32x16 acc2[2][2];
#pragma unroll
  for (int nt = 0; nt < 2; ++nt) for (int mt = 0; mt < 2; ++mt)
    for (int r = 0; r < 16; ++r) acc2[nt][mt][r] = 0.f;

#pragma unroll
  for (int k4 = 0; k4 < 8; ++k4) {
    int ck = k4*2 + kh;
    int sw = ck & 3;
    short8 bf_[2];
#pragma unroll
    for (int nt = 0; nt < 2; ++nt)
      bf_[nt] = *(const short8*)&Wt2c[(ck*256 + wv*64 + nt*32 + l31)*8];
    short8 a[2];
#pragma unroll
    for (int mt = 0; mt < 2; ++mt)
      a[mt] = *(const short8*)&X1c[(ck*64 + ((mt*32 + l31) ^ sw))*8];
#pragma unroll
    for (int nt = 0; nt < 2; ++nt)
#pragma unroll
      for (int mt = 0; mt < 2; ++mt)
        acc2[nt][mt] = MFMA32(a[mt], bf_[nt], acc2[nt][mt]);
  }

  // ---- stats2 + per-32-row max/min (p = blockIdx*2 + mt) ----
  int slot = blockIdx.x & 7;
#pragma unroll
  for (int nt = 0; nt < 2; ++nt) {
    float s = 0.f, q = 0.f;
    float mx[2] = {-3.0e38f, -3.0e38f}, mn[2] = {3.0e38f, 3.0e38f};
#pragma unroll
    for (int mt = 0; mt < 2; ++mt)
#pragma unroll
      for (int r = 0; r < 16; ++r) {
        float y = acc2[nt][mt][r];
        s += y; q += y*y;
        mx[mt] = fmaxf(mx[mt], y); mn[mt] = fminf(mn[mt], y);
      }
    s += __shfl_xor(s, 32); q += __shfl_xor(q, 32);
    mx[0] = fmaxf(mx[0], __shfl_xor(mx[0], 32));
    mx[1] = fmaxf(mx[1], __shfl_xor(mx[1], 32));
    mn[0] = fminf(mn[0], __shfl_xor(mn[0], 32));
    mn[1] = fminf(mn[1], __shfl_xor(mn[1], 32));
    if (lane < 32) {
      int c = wv*64 + nt*32 + lane;
      atomicAdd(&stOut[slot*256 + c], s);
      atomicAdd(&stOut[2048 + slot*256 + c], q);
#pragma unroll
      for (int mt = 0; mt < 2; ++mt) {
        size_t pr = (size_t)blockIdx.x*2 + mt;
        mxp[pr*H2 + c] = f2bf(mx[mt]);
        mnp[pr*H2 + c] = f2bf(mn[mt]);
      }
    }
  }
}

// ---------------------------------------------------------------------------
// k_final: BN2 sign is fixed per channel -> select mxp/mnp POINTER once,
// halving read traffic (identical selection semantics).
// ---------------------------------------------------------------------------
__global__ __launch_bounds__(256) void k_final(
    const u16* __restrict__ mxp, const u16* __restrict__ mnp,
    const float* __restrict__ gma, const float* __restrict__ bta,
    const float* __restrict__ stIn, float* __restrict__ out_np)
{
  __shared__ float tmp[256][33];
  int tid = threadIdx.x;
  int b = blockIdx.x >> 5;
  int p0 = (blockIdx.x & 31) * 32;

  float s = 0.f, q = 0.f;
  for (int sl = 0; sl < 8; ++sl) { s += stIn[sl*256 + tid]; q += stIn[2048 + sl*256 + tid]; }
  float mu = s*INV_M, var = q*INV_M - mu*mu;
  float sc = gma[tid] * rsqrtf(var + BN_EPS);
  float sh = bta[tid] - mu*sc;
  const u16* src = (sc >= 0.f) ? mxp : mnp;   // per-channel fixed selection

  for (int pp = 0; pp < 32; ++pp) {
    size_t base = ((size_t)(b*NPP + p0 + pp))*H2 + tid;
    float v = fmaf(sc, bf2f(src[base]), sh);
    tmp[tid][pp] = fmaxf(v, 0.f);
  }
  __syncthreads();

  int pl = tid & 31, cg = tid >> 5;
  for (int cc = 0; cc < 32; ++cc) {
    int c = cc*8 + cg;
    out_np[((size_t)b*H2 + c)*NPP + p0 + pl] = tmp[c][pl];
  }
}

// ---------------------------------------------------------------------------
extern "C" void kernel_launch(void* const* d_in, const int* in_sizes, int n_in,
                              void* d_out, int out_size, void* d_ws, size_t ws_size,
                              hipStream_t stream)
{
  const float* xyz    = (const float*)d_in[0];
  const float* points = (const float*)d_in[1];
  const int*   sidx   = (const int*)d_in[2];
  const int*   nidx   = (const int*)d_in[3];
  const float* W0 = (const float*)d_in[4];
  const float* g0 = (const float*)d_in[6];
  const float* e0 = (const float*)d_in[7];
  const float* W1 = (const float*)d_in[8];
  const float* g1 = (const float*)d_in[10];
  const float* e1 = (const float*)d_in[11];
  const float* W2 = (const float*)d_in[12];
  const float* g2 = (const float*)d_in[14];
  const float* e2 = (const float*)d_in[15];

  float* out_xyz = (float*)d_out;
  float* out_np  = out_xyz + (size_t)BB*NPP*3;

  if (ws_size < (size_t)WS_NEED) {
    hipMemsetAsync(out_np, 0, (size_t)BB*H2*NPP*4, stream);
    k_xyz_only<<<32, 256, 0, stream>>>(xyz, sidx, out_xyz);
    return;
  }

  char* ws = (char*)d_ws;
  float* stats = (float*)(ws + 0);
  u16*   Wt0c  = (u16*)(ws + 49152);
  u16*   Wt1c  = (u16*)(ws + 61440);
  u16*   Wt2c  = (u16*)(ws + 77824);
  u16*   ptsT  = (u16*)(ws + 143360);
  u16*   y0    = (u16*)(ws + 4337664);
  u16*   mxp   = (u16*)(ws + 37892096);
  u16*   mnp   = (u16*)(ws + 42086400);

  k_setup<<<555, 256, 0, stream>>>(xyz, points, sidx, W0, W1, W2,
                                   ptsT, Wt0c, Wt1c, Wt2c, out_xyz, stats);
  k_l0<<<MTOT/128, 256, 0, stream>>>(xyz, sidx, nidx, ptsT, Wt0c, y0, stats);
  k_l1s<<<MTOT/128, 256, 0, stream>>>(y0, Wt1c, g0, e0, stats, stats + 4096);
  k_l2f<<<MTOT/64, 256, 0, stream>>>(y0, Wt1c, Wt2c, g0, e0, g1, e1,
                                     stats, stats + 4096, stats + 8192, mxp, mnp);
  k_final<<<256, 256, 0, stream>>>(mxp, mnp, g2, e2, stats + 8192, out_np);
}

// Round 16
// 164.850 us; speedup vs baseline: 1.0276x; 1.0276x over previous
//
#include <hip/hip_runtime.h>

typedef unsigned short u16;
typedef unsigned int u32;
typedef __attribute__((ext_vector_type(8))) short short8;    // 8 bf16
typedef __attribute__((ext_vector_type(16))) float f32x16;

#define BB 8
#define NN 4096
#define NPP 1024
#define NSS 32
#define CFF 64
#define C0 67
#define H0 64
#define H1 128
#define H2 256
#define MTOT (BB*NPP*NSS)   // 262144
#define BN_EPS 1e-5f
#define INV_M (1.0f/262144.0f)

#define MFMA32(a,b,c) __builtin_amdgcn_mfma_f32_32x32x16_bf16(a,b,c,0,0,0)

__device__ __forceinline__ float bf2f(u16 h){ return __uint_as_float(((u32)h)<<16); }
__device__ __forceinline__ u16 f2bf(float f){
  u32 u = __float_as_uint(f);
  u32 r = (u + 0x7fffu + ((u>>16)&1u)) >> 16;
  return (u16)r;
}
__device__ __forceinline__ u32 pack2(float a, float b){
  return (u32)f2bf(a) | ((u32)f2bf(b)<<16);
}

// ---------------------------------------------------------------------------
// FINAL ARTIFACT (session closed at practical plateau ~167 us; best 166.5).
// Structure: 5-dispatch pipeline, HW command-processor phase boundaries.
// Tested & closed this session: micro-opts (null x5), Gram stats (regress),
// persistent loops (spill), cooperative launch (no-op in harness), software
// grid barriers (2.7x regress), dead-work cuts (null). Remaining gap is
// inter-phase serialization (3 global BN-stats reductions) + harness fill.
//
// Chunked-K layout: [k/8][row][8 bf16]; MFMA 32x32x16: A[m=lane&31][k=(lane>>5)*8+j]
// (k-perm consistent across A/B => exact), C/D col=lane&31,
// row=(reg&3)+8*(reg>>2)+4*(lane>>5).
//
// ws layout (bytes), total 46,280,704:
//   stats [0,49152) | Wt0c [49152,61440) | Wt1c [61440,77824) | Wt2c [77824,143360)
//   ptsT [143360,4337664) | y0 [4337664,37892096) | mxp [37892096,42086400)
//   mnp [42086400,46280704)
// ---------------------------------------------------------------------------
#define WS_NEED 46280704u

__global__ __launch_bounds__(256) void k_setup(
    const float* __restrict__ xyz, const float* __restrict__ points,
    const int* __restrict__ sidx,
    const float* __restrict__ W0, const float* __restrict__ W1, const float* __restrict__ W2,
    u16* __restrict__ ptsT, u16* __restrict__ Wt0c, u16* __restrict__ Wt1c,
    u16* __restrict__ Wt2c, float* __restrict__ out_newxyz, float* __restrict__ stats)
{
  int blk = blockIdx.x, tid = threadIdx.x;
  if (blk < 512) {
    __shared__ float t[64][68];          // pad 68: 16B-aligned rows, conflict-free
    int b = blk >> 6, n0 = (blk & 63) << 6;
    for (int it = 0; it < 4; ++it) {
      int u = it*256 + tid;              // 1024 units
      int nq = u & 15, c = u >> 4;       // c 0..63
      float4 v = *(const float4*)&points[(size_t)(b*CFF + c)*NN + n0 + nq*4];
      *(float4*)&t[c][nq*4] = v;
    }
    __syncthreads();
    for (int it = 0; it < 2; ++it) {
      int u = it*256 + tid;              // 512 units
      int oct = u & 7, n = u >> 3;       // n 0..63
      u16 pk[8];
#pragma unroll
      for (int j = 0; j < 8; ++j) pk[j] = f2bf(t[oct*8 + j][n]);
      *(uint4*)&ptsT[((size_t)(b*NN + n0 + n))*CFF + oct*8] = *(uint4*)pk;
    }
  } else if (blk < 544) {
    int t0 = (blk - 512)*256 + tid;
    int b = t0 >> 10;
    int s = sidx[t0];
    for (int k = 0; k < 3; ++k)
      out_newxyz[(size_t)t0*3 + k] = xyz[((size_t)(b*NN + s))*3 + k];
  } else if (blk == 544) {
    for (int i = 0; i < 24; ++i) {
      int e = i*256 + tid;                 // [12 kc][64 o][8 j]
      int kc = e >> 9, o = (e >> 3) & 63, j = e & 7, k = kc*8 + j;
      float v = (k < 64) ? W0[o*C0 + 3 + k] : ((k < 67) ? W0[o*C0 + (k - 64)] : 0.f);
      Wt0c[e] = f2bf(v);
    }
  } else if (blk == 545) {
    for (int i = 0; i < 32; ++i) {
      int e = i*256 + tid;                 // [8 kc][128 n][8 j]
      int kc = e >> 10, n = (e >> 3) & 127, j = e & 7;
      Wt1c[e] = f2bf(W1[n*H0 + kc*8 + j]);
    }
  } else if (blk == 554) {
    // zero the 3x4096-float stats region (replaces hipMemsetAsync dispatch)
    float4 z = {0.f, 0.f, 0.f, 0.f};
    float4* p = (float4*)stats;
#pragma unroll
    for (int i = 0; i < 12; ++i) p[i*256 + tid] = z;
  } else {
    int base = (blk - 546) * 4096;
    for (int i = 0; i < 16; ++i) {
      int e = base + i*256 + tid;          // [16 kc][256 n][8 j]
      int kc = e >> 11, n = (e >> 3) & 255, j = e & 7;
      Wt2c[e] = f2bf(W2[n*H1 + kc*8 + j]);
    }
  }
}

__global__ __launch_bounds__(256) void k_xyz_only(
    const float* __restrict__ xyz, const int* __restrict__ sidx, float* __restrict__ out_newxyz)
{
  int t0 = blockIdx.x*256 + threadIdx.x;
  int b = t0 >> 10;
  int s = sidx[t0];
  for (int k = 0; k < 3; ++k)
    out_newxyz[(size_t)t0*3 + k] = xyz[((size_t)(b*NN + s))*3 + k];
}

// ---------------------------------------------------------------------------
// L0: M=128, K=96 (12 chunks), Cout=64. Epilogue: LDS transpose -> coalesced
// dwordx4 y0 stores.
// ---------------------------------------------------------------------------
__global__ __launch_bounds__(256) void k_l0(
    const float* __restrict__ xyz, const int* __restrict__ sidx, const int* __restrict__ nidx,
    const u16* __restrict__ ptsT, const u16* __restrict__ Wt0c,
    u16* __restrict__ y0, float* __restrict__ stats)
{
  __shared__ u16 XLc[12*128*8];  // 24 KB (reused as 16 KB C-stage in epilogue)
  __shared__ u16 W0c[12*64*8];   // 12 KB
  int tid = threadIdx.x;
  int m0 = blockIdx.x * 128;
  int b = m0 >> 15;

  for (int i = 0; i < 3; ++i)
    ((uint4*)W0c)[i*256 + tid] = ((const uint4*)Wt0c)[i*256 + tid];

  int pos = tid & 127, half = tid >> 7;
  int m = m0 + pos;
  int nb = nidx[m];
  {
    const uint4* prow = (const uint4*)(ptsT + ((size_t)(b*NN + nb))*CFF + half*32);
    uint4 h0 = prow[0], h1 = prow[1], h2 = prow[2], h3 = prow[3];
    *(uint4*)&XLc[((half*4+0)*128 + pos)*8] = h0;
    *(uint4*)&XLc[((half*4+1)*128 + pos)*8] = h1;
    *(uint4*)&XLc[((half*4+2)*128 + pos)*8] = h2;
    *(uint4*)&XLc[((half*4+3)*128 + pos)*8] = h3;
    if (half == 0) {
      int p = (m & 32767) >> 5;
      int sp = sidx[b*NPP + p];
      float r0 = xyz[((size_t)(b*NN+nb))*3+0] - xyz[((size_t)(b*NN+sp))*3+0];
      float r1 = xyz[((size_t)(b*NN+nb))*3+1] - xyz[((size_t)(b*NN+sp))*3+1];
      float r2 = xyz[((size_t)(b*NN+nb))*3+2] - xyz[((size_t)(b*NN+sp))*3+2];
      uint4 v = { pack2(r0, r1), pack2(r2, 0.f), 0u, 0u };
      *(uint4*)&XLc[(8*128 + pos)*8] = v;
    } else {
      uint4 z = {0u,0u,0u,0u};
      *(uint4*)&XLc[(9*128 + pos)*8]  = z;
      *(uint4*)&XLc[(10*128 + pos)*8] = z;
      *(uint4*)&XLc[(11*128 + pos)*8] = z;
    }
  }
  __syncthreads();

  int lane = tid & 63, wv = tid >> 6;
  int l31 = lane & 31, kh = lane >> 5;
  int nt = wv & 1, mtb = (wv >> 1) * 2;
  f32x16 acc[2];
  for (int mi = 0; mi < 2; ++mi) for (int r = 0; r < 16; ++r) acc[mi][r] = 0.f;

  for (int kt = 0; kt < 6; ++kt) {
    int ck = kt*2 + kh;
    short8 bfrag = *(const short8*)&W0c[(ck*64 + nt*32 + l31)*8];
    for (int mi = 0; mi < 2; ++mi) {
      short8 afrag = *(const short8*)&XLc[(ck*128 + (mtb+mi)*32 + l31)*8];
      acc[mi] = MFMA32(afrag, bfrag, acc[mi]);
    }
  }

  float s = 0.f, q = 0.f;
  for (int mi = 0; mi < 2; ++mi)
    for (int r = 0; r < 16; ++r) { float y = acc[mi][r]; s += y; q += y*y; }
  s += __shfl_xor(s, 32); q += __shfl_xor(q, 32);
  if (lane < 32) {
    int slot = blockIdx.x & 7;
    atomicAdd(&stats[slot*256 + nt*32 + lane], s);
    atomicAdd(&stats[2048 + slot*256 + nt*32 + lane], q);
  }

  // ---- coalesced y0 write: scatter to LDS (reuse XLc), then dwordx4 ----
  __syncthreads();   // all MFMA ds_reads of XLc complete
  {
    int chx = (nt*32 + l31) ^ (kh*32);   // = l31 + 32*(nt^kh)
#pragma unroll
    for (int mi = 0; mi < 2; ++mi)
#pragma unroll
      for (int r = 0; r < 16; ++r) {
        int mm = (mtb+mi)*32 + (r&3) + 8*(r>>2) + 4*kh;   // mm bit2 == kh
        XLc[mm*64 + chx] = f2bf(acc[mi][r]);
      }
  }
  __syncthreads();
  {
    uint4* dst = (uint4*)(y0 + (size_t)m0*H0);
#pragma unroll
    for (int i = 0; i < 4; ++i) {
      int t16 = i*256 + tid;                 // 16B unit
      int mrow = t16 >> 3, ch0 = (t16 & 7)*8;
      int idx = mrow*64 + (ch0 ^ (32*((mrow>>2)&1)));
      dst[t16] = *(const uint4*)&XLc[idx];
    }
  }
}

// ---------------------------------------------------------------------------
// L1 stats v2: M=128, BN0+ReLU staged in 16KB X0c; W1 B-fragments DIRECT from
// global (per-wave coalesced 512B, issued before any barrier). (256,4).
// ---------------------------------------------------------------------------
__global__ __launch_bounds__(256, 4) void k_l1s(
    const u16* __restrict__ y0, const u16* __restrict__ Wt1c,
    const float* __restrict__ g0, const float* __restrict__ e0,
    const float* __restrict__ stIn, float* __restrict__ stOut)
{
  __shared__ u16 X0c[8*128*8];   // 16 KB
  __shared__ float scl0[64], sft0[64];
  int tid = threadIdx.x;
  int m0 = blockIdx.x * 128;
  int lane = tid & 63, wv = tid >> 6;
  int l31 = lane & 31, kh = lane >> 5;

  // early global loads: y0 row + B fragments (no LDS dependency)
  int pos = tid & 127, half = tid >> 7;
  u16 hs[32];
  {
    const u16* row = y0 + (size_t)(m0 + pos)*H0 + half*32;
#pragma unroll
    for (int t = 0; t < 4; ++t) *(uint4*)&hs[t*8] = ((const uint4*)row)[t];
  }
  short8 b1[4];
#pragma unroll
  for (int kt = 0; kt < 4; ++kt)
    b1[kt] = *(const short8*)&Wt1c[((kt*2 + kh)*128 + wv*32 + l31)*8];

  if (tid < 64) {
    float s = 0.f, q = 0.f;
    for (int sl = 0; sl < 8; ++sl) { s += stIn[sl*256 + tid]; q += stIn[2048 + sl*256 + tid]; }
    float mu = s*INV_M, var = q*INV_M - mu*mu;
    float sc = g0[tid] * rsqrtf(var + BN_EPS);
    scl0[tid] = sc; sft0[tid] = e0[tid] - mu*sc;
  }
  __syncthreads();   // scl0 ready

  {
    u16 ob[32];
#pragma unroll
    for (int j = 0; j < 32; ++j) {
      int c = half*32 + j;
      ob[j] = f2bf(fmaxf(fmaf(scl0[c], bf2f(hs[j]), sft0[c]), 0.f));
    }
#pragma unroll
    for (int t = 0; t < 4; ++t)
      *(uint4*)&X0c[((half*4+t)*128 + pos)*8] = *(uint4*)&ob[t*8];
  }
  __syncthreads();

  f32x16 acc[4];
#pragma unroll
  for (int mt = 0; mt < 4; ++mt) for (int r = 0; r < 16; ++r) acc[mt][r] = 0.f;

#pragma unroll
  for (int kt = 0; kt < 4; ++kt) {
    int ck = kt*2 + kh;
#pragma unroll
    for (int mt = 0; mt < 4; ++mt) {
      short8 afrag = *(const short8*)&X0c[(ck*128 + mt*32 + l31)*8];
      acc[mt] = MFMA32(afrag, b1[kt], acc[mt]);
    }
  }

  float s = 0.f, q = 0.f;
#pragma unroll
  for (int mt = 0; mt < 4; ++mt)
#pragma unroll
    for (int r = 0; r < 16; ++r) { float y = acc[mt][r]; s += y; q += y*y; }
  s += __shfl_xor(s, 32); q += __shfl_xor(q, 32);
  if (lane < 32) {
    int slot = blockIdx.x & 7;
    atomicAdd(&stOut[slot*256 + wv*32 + lane], s);
    atomicAdd(&stOut[2048 + slot*256 + wv*32 + lane], q);
  }
}

// ---------------------------------------------------------------------------
// L2 fused v4: M=64, 256 threads, 24KB LDS, no weight staging (W1/W2 direct
// per-wave register fragments from L2-hot Wt1c/Wt2c). (256,4). 3 barriers.
// X1c row-XOR-swizzle by (cb&3) as verified in R2.
// ---------------------------------------------------------------------------
__global__ __launch_bounds__(256, 4) void k_l2f(
    const u16* __restrict__ y0, const u16* __restrict__ Wt1c, const u16* __restrict__ Wt2c,
    const float* __restrict__ g0, const float* __restrict__ e0,
    const float* __restrict__ g1, const float* __restrict__ e1,
    const float* __restrict__ st0, const float* __restrict__ st1, float* __restrict__ stOut,
    u16* __restrict__ mxp, u16* __restrict__ mnp)
{
  __shared__ u16 X0c[8*64*8];     // 8 KB
  __shared__ u16 X1c[16*64*8];    // 16 KB, rows XOR-swizzled by (cb&3)
  __shared__ float scl0[64], sft0[64], scl1[128], sft1[128];
  int tid = threadIdx.x;
  int m0 = blockIdx.x * 64;
  int lane = tid & 63, wv = tid >> 6;
  int l31 = lane & 31, kh = lane >> 5;

  // early global loads: y0 rows + W1 fragments
  int pos = tid & 63, grp = tid >> 6;
  u16 hs[16];
  {
    const u16* row = y0 + (size_t)(m0 + pos)*H0 + grp*16;
    *(uint4*)&hs[0] = ((const uint4*)row)[0];
    *(uint4*)&hs[8] = ((const uint4*)row)[1];
  }
  short8 b1[4];
#pragma unroll
  for (int kt = 0; kt < 4; ++kt)
    b1[kt] = *(const short8*)&Wt1c[((kt*2 + kh)*128 + wv*32 + l31)*8];

  if (tid < 64) {
    float s = 0.f, q = 0.f;
    for (int sl = 0; sl < 8; ++sl) { s += st0[sl*256 + tid]; q += st0[2048 + sl*256 + tid]; }
    float mu = s*INV_M, var = q*INV_M - mu*mu;
    float sc = g0[tid] * rsqrtf(var + BN_EPS);
    scl0[tid] = sc; sft0[tid] = e0[tid] - mu*sc;
  }
  if (tid < 128) {
    float s = 0.f, q = 0.f;
    for (int sl = 0; sl < 8; ++sl) { s += st1[sl*256 + tid]; q += st1[2048 + sl*256 + tid]; }
    float mu = s*INV_M, var = q*INV_M - mu*mu;
    float sc = g1[tid] * rsqrtf(var + BN_EPS);
    scl1[tid] = sc; sft1[tid] = e1[tid] - mu*sc;
  }
  __syncthreads();   // scl0/scl1 ready

  // BN0+ReLU -> X0c
  {
    u16 ob[16];
#pragma unroll
    for (int j = 0; j < 16; ++j) {
      int c = grp*16 + j;
      ob[j] = f2bf(fmaxf(fmaf(scl0[c], bf2f(hs[j]), sft0[c]), 0.f));
    }
    *(uint4*)&X0c[((2*grp)*64 + pos)*8]   = *(uint4*)&ob[0];
    *(uint4*)&X0c[((2*grp+1)*64 + pos)*8] = *(uint4*)&ob[8];
  }
  __syncthreads();

  // ---- GEMM1: wave wv -> out-ch wv*32+l31, rows mt*32 (mt 0..1) ----
  f32x16 acc1[2];
#pragma unroll
  for (int mt = 0; mt < 2; ++mt) for (int r = 0; r < 16; ++r) acc1[mt][r] = 0.f;
#pragma unroll
  for (int kt = 0; kt < 4; ++kt) {
    int ck = kt*2 + kh;
#pragma unroll
    for (int mt = 0; mt < 2; ++mt) {
      short8 afrag = *(const short8*)&X0c[(ck*64 + mt*32 + l31)*8];
      acc1[mt] = MFMA32(afrag, b1[kt], acc1[mt]);
    }
  }

  // ---- BN1+ReLU scatter C->A into X1c (row XOR-swizzled by cb&3) ----
  {
    int ch1 = wv*32 + l31;
    int cb = ch1 >> 3, cr = ch1 & 7, sw = cb & 3;
    float sc1 = scl1[ch1], sf1 = sft1[ch1];
#pragma unroll
    for (int mt = 0; mt < 2; ++mt)
#pragma unroll
      for (int r = 0; r < 16; ++r) {
        int mm = mt*32 + (r&3) + 8*(r>>2) + 4*kh;
        X1c[(cb*64 + (mm ^ sw))*8 + cr] = f2bf(fmaxf(fmaf(sc1, acc1[mt][r], sf1), 0.f));
      }
  }
  __syncthreads();

  // ---- GEMM2: wave wv -> out-ch wv*64 + nt*32 + l31; K=128, k4 0..7 ----
  f32x16 acc2[2][2];
#pragma unroll
  for (int nt = 0; nt < 2; ++nt) for (int mt = 0; mt < 2; ++mt)
    for (int r = 0; r < 16; ++r) acc2[nt][mt][r] = 0.f;

#pragma unroll
  for (int k4 = 0; k4 < 8; ++k4) {
    int ck = k4*2 + kh;
    int sw = ck & 3;
    short8 bf_[2];
#pragma unroll
    for (int nt = 0; nt < 2; ++nt)
      bf_[nt] = *(const short8*)&Wt2c[(ck*256 + wv*64 + nt*32 + l31)*8];
    short8 a[2];
#pragma unroll
    for (int mt = 0; mt < 2; ++mt)
      a[mt] = *(const short8*)&X1c[(ck*64 + ((mt*32 + l31) ^ sw))*8];
#pragma unroll
    for (int nt = 0; nt < 2; ++nt)
#pragma unroll
      for (int mt = 0; mt < 2; ++mt)
        acc2[nt][mt] = MFMA32(a[mt], bf_[nt], acc2[nt][mt]);
  }

  // ---- stats2 + per-32-row max/min (p = blockIdx*2 + mt) ----
  int slot = blockIdx.x & 7;
#pragma unroll
  for (int nt = 0; nt < 2; ++nt) {
    float s = 0.f, q = 0.f;
    float mx[2] = {-3.0e38f, -3.0e38f}, mn[2] = {3.0e38f, 3.0e38f};
#pragma unroll
    for (int mt = 0; mt < 2; ++mt)
#pragma unroll
      for (int r = 0; r < 16; ++r) {
        float y = acc2[nt][mt][r];
        s += y; q += y*y;
        mx[mt] = fmaxf(mx[mt], y); mn[mt] = fminf(mn[mt], y);
      }
    s += __shfl_xor(s, 32); q += __shfl_xor(q, 32);
    mx[0] = fmaxf(mx[0], __shfl_xor(mx[0], 32));
    mx[1] = fmaxf(mx[1], __shfl_xor(mx[1], 32));
    mn[0] = fminf(mn[0], __shfl_xor(mn[0], 32));
    mn[1] = fminf(mn[1], __shfl_xor(mn[1], 32));
    if (lane < 32) {
      int c = wv*64 + nt*32 + lane;
      atomicAdd(&stOut[slot*256 + c], s);
      atomicAdd(&stOut[2048 + slot*256 + c], q);
#pragma unroll
      for (int mt = 0; mt < 2; ++mt) {
        size_t pr = (size_t)blockIdx.x*2 + mt;
        mxp[pr*H2 + c] = f2bf(mx[mt]);
        mnp[pr*H2 + c] = f2bf(mn[mt]);
      }
    }
  }
}

// ---------------------------------------------------------------------------
__global__ __launch_bounds__(256) void k_final(
    const u16* __restrict__ mxp, const u16* __restrict__ mnp,
    const float* __restrict__ gma, const float* __restrict__ bta,
    const float* __restrict__ stIn, float* __restrict__ out_np)
{
  __shared__ float tmp[256][33];
  int tid = threadIdx.x;
  int b = blockIdx.x >> 5;
  int p0 = (blockIdx.x & 31) * 32;

  float s = 0.f, q = 0.f;
  for (int sl = 0; sl < 8; ++sl) { s += stIn[sl*256 + tid]; q += stIn[2048 + sl*256 + tid]; }
  float mu = s*INV_M, var = q*INV_M - mu*mu;
  float sc = gma[tid] * rsqrtf(var + BN_EPS);
  float sh = bta[tid] - mu*sc;

  for (int pp = 0; pp < 32; ++pp) {
    size_t base = ((size_t)(b*NPP + p0 + pp))*H2 + tid;
    float xv = bf2f(mxp[base]), nv = bf2f(mnp[base]);
    float v = (sc >= 0.f) ? fmaf(sc, xv, sh) : fmaf(sc, nv, sh);
    tmp[tid][pp] = fmaxf(v, 0.f);
  }
  __syncthreads();

  int pl = tid & 31, cg = tid >> 5;
  for (int cc = 0; cc < 32; ++cc) {
    int c = cc*8 + cg;
    out_np[((size_t)b*H2 + c)*NPP + p0 + pl] = tmp[c][pl];
  }
}

// ---------------------------------------------------------------------------
extern "C" void kernel_launch(void* const* d_in, const int* in_sizes, int n_in,
                              void* d_out, int out_size, void* d_ws, size_t ws_size,
                              hipStream_t stream)
{
  const float* xyz    = (const float*)d_in[0];
  const float* points = (const float*)d_in[1];
  const int*   sidx   = (const int*)d_in[2];
  const int*   nidx   = (const int*)d_in[3];
  const float* W0 = (const float*)d_in[4];
  const float* g0 = (const float*)d_in[6];
  const float* e0 = (const float*)d_in[7];
  const float* W1 = (const float*)d_in[8];
  const float* g1 = (const float*)d_in[10];
  const float* e1 = (const float*)d_in[11];
  const float* W2 = (const float*)d_in[12];
  const float* g2 = (const float*)d_in[14];
  const float* e2 = (const float*)d_in[15];

  float* out_xyz = (float*)d_out;
  float* out_np  = out_xyz + (size_t)BB*NPP*3;

  if (ws_size < (size_t)WS_NEED) {
    hipMemsetAsync(out_np, 0, (size_t)BB*H2*NPP*4, stream);
    k_xyz_only<<<32, 256, 0, stream>>>(xyz, sidx, out_xyz);
    return;
  }

  char* ws = (char*)d_ws;
  float* stats = (float*)(ws + 0);
  u16*   Wt0c  = (u16*)(ws + 49152);
  u16*   Wt1c  = (u16*)(ws + 61440);
  u16*   Wt2c  = (u16*)(ws + 77824);
  u16*   ptsT  = (u16*)(ws + 143360);
  u16*   y0    = (u16*)(ws + 4337664);
  u16*   mxp   = (u16*)(ws + 37892096);
  u16*   mnp   = (u16*)(ws + 42086400);

  k_setup<<<555, 256, 0, stream>>>(xyz, points, sidx, W0, W1, W2,
                                   ptsT, Wt0c, Wt1c, Wt2c, out_xyz, stats);
  k_l0<<<MTOT/128, 256, 0, stream>>>(xyz, sidx, nidx, ptsT, Wt0c, y0, stats);
  k_l1s<<<MTOT/128, 256, 0, stream>>>(y0, Wt1c, g0, e0, stats, stats + 4096);
  k_l2f<<<MTOT/64, 256, 0, stream>>>(y0, Wt1c, Wt2c, g0, e0, g1, e1,
                                     stats, stats + 4096, stats + 8192, mxp, mnp);
  k_final<<<256, 256, 0, stream>>>(mxp, mnp, g2, e2, stats + 8192, out_np);
}